// Round 5
// baseline (414.093 us; speedup 1.0000x reference)
//
#include <hip/hip_runtime.h>
#include <hip/hip_bf16.h>

typedef __bf16 bf16_t;
typedef __bf16 bf16x4 __attribute__((ext_vector_type(4)));
typedef __bf16 bf16x8 __attribute__((ext_vector_type(8)));
typedef float floatx4 __attribute__((ext_vector_type(4)));

#define NB 4
#define NH 12
#define SEQ 2048
#define DM 768
#define LOG2E 1.44269504088896340736f

__device__ __forceinline__ void async_copy16(const bf16_t* g, bf16_t* l) {
  __builtin_amdgcn_global_load_lds(
      (const __attribute__((address_space(1))) void*)g,
      (__attribute__((address_space(3))) void*)l, 16, 0, 0);
}

// ---------------------------------------------------------------- cvt f32->bf16
__global__ __launch_bounds__(256) void cvt_kernel(const float* __restrict__ in,
                                                  bf16_t* __restrict__ out) {
  int i = (blockIdx.x * 256 + threadIdx.x) * 4;
  float4 v = *(const float4*)(in + i);
  bf16x4 h;
  h[0] = (bf16_t)v.x; h[1] = (bf16_t)v.y; h[2] = (bf16_t)v.z; h[3] = (bf16_t)v.w;
  *(bf16x4*)(out + i) = h;
}

// ---------------------------------------------- transpose + cvt: in[K][N] -> out[N][K]
__global__ __launch_bounds__(256) void transpose_cvt_kernel(const float* __restrict__ in,
                                                            bf16_t* __restrict__ out,
                                                            int K, int N) {
  __shared__ float tile[32][33];
  int nb = blockIdx.x * 32, kb = blockIdx.y * 32;
  int tx = threadIdx.x & 31, ty = threadIdx.x >> 5;
#pragma unroll
  for (int r = ty; r < 32; r += 8)
    tile[r][tx] = in[(size_t)(kb + r) * N + nb + tx];
  __syncthreads();
#pragma unroll
  for (int r = ty; r < 32; r += 8)
    out[(size_t)(nb + r) * K + kb + tx] = (bf16_t)tile[tx][r];
}

// ---------------------------------------------------------------- QKV GEMM (m97-style)
__global__ __launch_bounds__(256, 3) void gemm_qkv_kernel(
    const bf16_t* __restrict__ A, const bf16_t* __restrict__ BT,
    const float* __restrict__ bias,
    bf16_t* __restrict__ Qo, bf16_t* __restrict__ Ko, bf16_t* __restrict__ Vo) {
  const int K = 768;
  __shared__ __align__(16) bf16_t As[128 * 32];  // [m][k], unpadded (async staging)
  __shared__ __align__(16) bf16_t Bs[128 * 32];  // [n][k]
  int m0 = blockIdx.x * 128, n0 = blockIdx.y * 128;
  int tid = threadIdx.x;
  int w = tid >> 6, lane = tid & 63, quad = lane >> 4, l16 = lane & 15;
  int wm = (w >> 1) * 64, wn = (w & 1) * 64;
  const bf16_t* gA = A + (size_t)(m0 + w * 32 + (lane >> 2)) * K + (lane & 3) * 8;
  const bf16_t* gB = BT + (size_t)(n0 + w * 32 + (lane >> 2)) * K + (lane & 3) * 8;
  bf16_t* lA = &As[(w * 32) * 32];
  bf16_t* lB = &Bs[(w * 32) * 32];
  floatx4 acc[4][4];
#pragma unroll
  for (int i = 0; i < 4; i++)
#pragma unroll
    for (int j = 0; j < 4; j++) acc[i][j] = (floatx4)(0.f);
  for (int k0 = 0; k0 < K; k0 += 32) {
    __syncthreads();
    async_copy16(gA + k0, lA);
    async_copy16(gA + 16 * K + k0, lA + 16 * 32);
    async_copy16(gB + k0, lB);
    async_copy16(gB + 16 * K + k0, lB + 16 * 32);
    __syncthreads();
    bf16x8 af[4], bfr[4];
#pragma unroll
    for (int i = 0; i < 4; i++)
      af[i] = *(const bf16x8*)&As[(wm + i * 16 + l16) * 32 + quad * 8];
#pragma unroll
    for (int j = 0; j < 4; j++)
      bfr[j] = *(const bf16x8*)&Bs[(wn + j * 16 + l16) * 32 + quad * 8];
#pragma unroll
    for (int i = 0; i < 4; i++)
#pragma unroll
      for (int j = 0; j < 4; j++)
        acc[i][j] = __builtin_amdgcn_mfma_f32_16x16x32_bf16(af[i], bfr[j], acc[i][j], 0, 0, 0);
  }
  int which = n0 / 768;
  bf16_t* dst = which == 0 ? Qo : (which == 1 ? Ko : Vo);
  float qscale = which == 0 ? (0.125f * LOG2E) : 1.0f;
  int rem_base = (n0 % 768) + wn;
#pragma unroll
  for (int j = 0; j < 4; j++) {
    int gc = n0 + wn + j * 16 + l16;
    int rem = rem_base + j * 16 + l16;
    int h = rem >> 6, hd = rem & 63;
    float bv = bias[gc];
#pragma unroll
    for (int i = 0; i < 4; i++)
#pragma unroll
      for (int r = 0; r < 4; r++) {
        int gr = m0 + wm + i * 16 + quad * 4 + r;
        int bb = gr >> 11, s = gr & 2047;
        float val = (acc[i][j][r] + bv) * qscale;
        dst[((size_t)((bb * NH + h) * SEQ + s)) * 64 + hd] = (bf16_t)val;
      }
  }
}

// ---------------------------------------------------------------- V transpose
__global__ __launch_bounds__(256) void vtrans_kernel(const bf16_t* __restrict__ V,
                                                     bf16_t* __restrict__ Vt) {
  __shared__ bf16_t tile[64][66];
  int bh = blockIdx.y, s0 = blockIdx.x * 64;
  int tid = threadIdx.x;
  int r = tid >> 4, c4 = (tid & 15) * 4;
  const bf16_t* src = V + (size_t)bh * SEQ * 64;
#pragma unroll
  for (int rr = r; rr < 64; rr += 16)
    *(bf16x4*)&tile[rr][c4] = *(const bf16x4*)&src[(size_t)(s0 + rr) * 64 + c4];
  __syncthreads();
  bf16_t* dst = Vt + (size_t)bh * 64 * SEQ;
#pragma unroll
  for (int hd = r; hd < 64; hd += 16) {
    bf16x4 o;
    o[0] = tile[c4 + 0][hd]; o[1] = tile[c4 + 1][hd];
    o[2] = tile[c4 + 2][hd]; o[3] = tile[c4 + 3][hd];
    *(bf16x4*)&dst[(size_t)hd * SEQ + s0 + c4] = o;
  }
}

// ---------------------------------------------------------------- flash attention
// 1-wave blocks, grid (64 pairs heavy-first, 48 bh). Each wave owns rows
// [r0, r0+32): two ADJACENT 16-row sets sharing one trip count -> minimal
// iterations (R4 lesson: iterations dominate; unequal pairing cost +47%).
// 1-wave blocks give fine-grained backfill (R2's 4-wave blocks drained at
// 18.5% occupancy). All loops statically unrolled (R3 scratch-spill lesson).
__global__ __launch_bounds__(64, 4) void attn_kernel(
    const bf16_t* __restrict__ Q, const bf16_t* __restrict__ Kg,
    const bf16_t* __restrict__ Vt, bf16_t* __restrict__ Out) {
  __shared__ __align__(16) bf16_t Ps[2][16][68];  // per row-set slab
  const int lane = threadIdx.x & 63;
  const int quad = lane >> 4, l16 = lane & 15;
  const int bh = blockIdx.y;
  const int b = bh / NH, h = bh % NH;
  const int r0 = (63 - (int)blockIdx.x) * 32;     // heavy-first
  const bf16_t* Qp = Q + (size_t)bh * SEQ * 64;
  const bf16_t* Kp = Kg + (size_t)bh * SEQ * 64;
  const bf16_t* Vp = Vt + (size_t)bh * 64 * SEQ;

  bf16x8 qf[2][2];
#pragma unroll
  for (int rs = 0; rs < 2; rs++)
#pragma unroll
    for (int hh = 0; hh < 2; hh++)
      qf[rs][hh] = *(const bf16x8*)&Qp[(size_t)(r0 + rs * 16 + l16) * 64 + hh * 32 + quad * 8];

  const int nt = (r0 >> 6) + 1;  // covers keys 0 .. r0+31 (last tile part-masked)

  float m_i[2][4], l_p[2][4];
  floatx4 acc[2][4];
#pragma unroll
  for (int rs = 0; rs < 2; rs++) {
#pragma unroll
    for (int r = 0; r < 4; r++) { m_i[rs][r] = -1e30f; l_p[rs][r] = 0.f; }
#pragma unroll
    for (int ot = 0; ot < 4; ot++) acc[rs][ot] = (floatx4)(0.f);
  }

  for (int kt = 0; kt < nt; kt++) {
    const int kbase = kt * 64;
    // ---- K fragments (direct from global, L2-resident)
    bf16x8 kf[4][2];
#pragma unroll
    for (int ct = 0; ct < 4; ct++)
#pragma unroll
      for (int hh = 0; hh < 2; hh++)
        kf[ct][hh] = *(const bf16x8*)&Kp[(size_t)(kbase + ct * 16 + l16) * 64 + hh * 32 + quad * 8];
    // ---- QK^T: both row-sets, same K fragments
    floatx4 s[2][4];
#pragma unroll
    for (int rs = 0; rs < 2; rs++)
#pragma unroll
      for (int ct = 0; ct < 4; ct++) {
        floatx4 z = (floatx4)(0.f);
        z = __builtin_amdgcn_mfma_f32_16x16x32_bf16(qf[rs][0], kf[ct][0], z, 0, 0, 0);
        z = __builtin_amdgcn_mfma_f32_16x16x32_bf16(qf[rs][1], kf[ct][1], z, 0, 0, 0);
        s[rs][ct] = z;
      }
    // ---- V fragments: issued now, consumed after softmax (fly across VALU)
    bf16x8 vf[4][2];
#pragma unroll
    for (int ot = 0; ot < 4; ot++)
#pragma unroll
      for (int kh = 0; kh < 2; kh++)
        vf[ot][kh] = *(const bf16x8*)&Vp[(size_t)(ot * 16 + l16) * SEQ + kbase + kh * 32 + quad * 8];
    // ---- causal mask (last tile only; both sets)
    if (kt == nt - 1) {
#pragma unroll
      for (int rs = 0; rs < 2; rs++)
#pragma unroll
        for (int ct = 0; ct < 4; ct++) {
          int key = kbase + ct * 16 + l16;
#pragma unroll
          for (int r = 0; r < 4; r++)
            if (key > r0 + rs * 16 + quad * 4 + r) s[rs][ct][r] = -1e30f;
        }
    }
    // ---- online softmax (exp2 domain), both sets; writes to private slabs
    asm volatile("s_waitcnt lgkmcnt(0)" ::: "memory");  // WAR vs prev pf reads
#pragma unroll
    for (int rs = 0; rs < 2; rs++) {
      float alpha_r[4];
#pragma unroll
      for (int r = 0; r < 4; r++) {
        float mt = fmaxf(fmaxf(s[rs][0][r], s[rs][1][r]), fmaxf(s[rs][2][r], s[rs][3][r]));
#pragma unroll
        for (int off = 8; off >= 1; off >>= 1)
          mt = fmaxf(mt, __shfl_xor(mt, off, 16));
        float mnew = fmaxf(m_i[rs][r], mt);
        float al = __builtin_amdgcn_exp2f(m_i[rs][r] - mnew);
        m_i[rs][r] = mnew;
        float p0 = __builtin_amdgcn_exp2f(s[rs][0][r] - mnew);
        float p1 = __builtin_amdgcn_exp2f(s[rs][1][r] - mnew);
        float p2 = __builtin_amdgcn_exp2f(s[rs][2][r] - mnew);
        float p3 = __builtin_amdgcn_exp2f(s[rs][3][r] - mnew);
        Ps[rs][quad * 4 + r][0 * 16 + l16] = (bf16_t)p0;
        Ps[rs][quad * 4 + r][1 * 16 + l16] = (bf16_t)p1;
        Ps[rs][quad * 4 + r][2 * 16 + l16] = (bf16_t)p2;
        Ps[rs][quad * 4 + r][3 * 16 + l16] = (bf16_t)p3;
        l_p[rs][r] = l_p[rs][r] * al + ((p0 + p1) + (p2 + p3));
        alpha_r[r] = al;
      }
#pragma unroll
      for (int ot = 0; ot < 4; ot++)
#pragma unroll
        for (int r = 0; r < 4; r++) acc[rs][ot][r] *= alpha_r[r];
    }
    // ---- P LDS roundtrip -> A-layout, then PV for both sets
    asm volatile("s_waitcnt lgkmcnt(0)" ::: "memory");  // RAW: P writes -> reads
#pragma unroll
    for (int rs = 0; rs < 2; rs++) {
      bf16x8 pf0 = *(const bf16x8*)&Ps[rs][l16][0 * 32 + quad * 8];
      bf16x8 pf1 = *(const bf16x8*)&Ps[rs][l16][1 * 32 + quad * 8];
#pragma unroll
      for (int ot = 0; ot < 4; ot++) {
        acc[rs][ot] = __builtin_amdgcn_mfma_f32_16x16x32_bf16(pf0, vf[ot][0], acc[rs][ot], 0, 0, 0);
        acc[rs][ot] = __builtin_amdgcn_mfma_f32_16x16x32_bf16(pf1, vf[ot][1], acc[rs][ot], 0, 0, 0);
      }
    }
  }
  // ---- epilogue
#pragma unroll
  for (int rs = 0; rs < 2; rs++) {
    float inv_l[4];
#pragma unroll
    for (int r = 0; r < 4; r++) {
      float ls = l_p[rs][r];
#pragma unroll
      for (int off = 8; off >= 1; off >>= 1)
        ls += __shfl_xor(ls, off, 16);
      inv_l[r] = __frcp_rn(ls);
    }
#pragma unroll
    for (int ot = 0; ot < 4; ot++)
#pragma unroll
      for (int r = 0; r < 4; r++) {
        int row = r0 + rs * 16 + quad * 4 + r;
        float o = acc[rs][ot][r] * inv_l[r];
        Out[((size_t)(b * SEQ + row)) * DM + h * 64 + ot * 16 + l16] = (bf16_t)o;
      }
  }
}

// ---------------------------------------------------------------- out-proj GEMM (m97-style)
__global__ __launch_bounds__(256, 3) void gemm_proj_kernel(
    const bf16_t* __restrict__ A, const bf16_t* __restrict__ BT,
    const float* __restrict__ bias, float* __restrict__ out) {
  const int K = 768;
  __shared__ __align__(16) bf16_t As[128 * 32];
  __shared__ __align__(16) bf16_t Bs[128 * 32];
  int m0 = blockIdx.x * 128, n0 = blockIdx.y * 128;
  int tid = threadIdx.x;
  int w = tid >> 6, lane = tid & 63, quad = lane >> 4, l16 = lane & 15;
  int wm = (w >> 1) * 64, wn = (w & 1) * 64;
  const bf16_t* gA = A + (size_t)(m0 + w * 32 + (lane >> 2)) * K + (lane & 3) * 8;
  const bf16_t* gB = BT + (size_t)(n0 + w * 32 + (lane >> 2)) * K + (lane & 3) * 8;
  bf16_t* lA = &As[(w * 32) * 32];
  bf16_t* lB = &Bs[(w * 32) * 32];
  floatx4 acc[4][4];
#pragma unroll
  for (int i = 0; i < 4; i++)
#pragma unroll
    for (int j = 0; j < 4; j++) acc[i][j] = (floatx4)(0.f);
  for (int k0 = 0; k0 < K; k0 += 32) {
    __syncthreads();
    async_copy16(gA + k0, lA);
    async_copy16(gA + 16 * K + k0, lA + 16 * 32);
    async_copy16(gB + k0, lB);
    async_copy16(gB + 16 * K + k0, lB + 16 * 32);
    __syncthreads();
    bf16x8 af[4], bfr[4];
#pragma unroll
    for (int i = 0; i < 4; i++)
      af[i] = *(const bf16x8*)&As[(wm + i * 16 + l16) * 32 + quad * 8];
#pragma unroll
    for (int j = 0; j < 4; j++)
      bfr[j] = *(const bf16x8*)&Bs[(wn + j * 16 + l16) * 32 + quad * 8];
#pragma unroll
    for (int i = 0; i < 4; i++)
#pragma unroll
      for (int j = 0; j < 4; j++)
        acc[i][j] = __builtin_amdgcn_mfma_f32_16x16x32_bf16(af[i], bfr[j], acc[i][j], 0, 0, 0);
  }
#pragma unroll
  for (int j = 0; j < 4; j++) {
    int gc = n0 + wn + j * 16 + l16;
    float bv = bias[gc];
#pragma unroll
    for (int i = 0; i < 4; i++)
#pragma unroll
      for (int r = 0; r < 4; r++) {
        int gr = m0 + wm + i * 16 + quad * 4 + r;
        out[(size_t)gr * 768 + gc] = acc[i][j][r] + bv;
      }
  }
}

// ---------------------------------------------------------------- launch
extern "C" void kernel_launch(void* const* d_in, const int* in_sizes, int n_in,
                              void* d_out, int out_size, void* d_ws, size_t ws_size,
                              hipStream_t stream) {
  const float* x      = (const float*)d_in[0];
  const float* w_qkv  = (const float*)d_in[1];
  const float* b_qkv  = (const float*)d_in[2];
  const float* w_proj = (const float*)d_in[3];
  const float* b_proj = (const float*)d_in[4];
  float* out = (float*)d_out;
  char* ws = (char*)d_ws;

  bf16_t* xb     = (bf16_t*)(ws + 0);         // dead after gemm_qkv; reused as vt
  bf16_t* wqkvT  = (bf16_t*)(ws + 12582912);
  bf16_t* wprojT = (bf16_t*)(ws + 16121856);
  bf16_t* q      = (bf16_t*)(ws + 17301504);
  bf16_t* k      = (bf16_t*)(ws + 29884416);
  bf16_t* v      = (bf16_t*)(ws + 42467328);
  bf16_t* ao     = (bf16_t*)(ws + 55050240);
  bf16_t* vt     = xb;

  cvt_kernel<<<6144, 256, 0, stream>>>(x, xb);
  transpose_cvt_kernel<<<dim3(72, 24), 256, 0, stream>>>(w_qkv, wqkvT, 768, 2304);
  transpose_cvt_kernel<<<dim3(24, 24), 256, 0, stream>>>(w_proj, wprojT, 768, 768);
  gemm_qkv_kernel<<<dim3(64, 18), 256, 0, stream>>>(xb, wqkvT, b_qkv, q, k, v);
  vtrans_kernel<<<dim3(32, 48), 256, 0, stream>>>(v, vt);
  attn_kernel<<<dim3(64, 48), 64, 0, stream>>>(q, k, vt, ao);
  gemm_proj_kernel<<<dim3(64, 6), 256, 0, stream>>>(ao, wprojT, b_proj, out);
}

// Round 6
// 322.309 us; speedup vs baseline: 1.2848x; 1.2848x over previous
//
#include <hip/hip_runtime.h>
#include <hip/hip_bf16.h>

typedef __bf16 bf16_t;
typedef __bf16 bf16x4 __attribute__((ext_vector_type(4)));
typedef __bf16 bf16x8 __attribute__((ext_vector_type(8)));
typedef float floatx4 __attribute__((ext_vector_type(4)));

#define NB 4
#define NH 12
#define SEQ 2048
#define DM 768
#define LOG2E 1.44269504088896340736f

__device__ __forceinline__ void async_copy16(const bf16_t* g, bf16_t* l) {
  __builtin_amdgcn_global_load_lds(
      (const __attribute__((address_space(1))) void*)g,
      (__attribute__((address_space(3))) void*)l, 16, 0, 0);
}

// ---------------------------------------------------------------- cvt f32->bf16
__global__ __launch_bounds__(256) void cvt_kernel(const float* __restrict__ in,
                                                  bf16_t* __restrict__ out) {
  int i = (blockIdx.x * 256 + threadIdx.x) * 4;
  float4 v = *(const float4*)(in + i);
  bf16x4 h;
  h[0] = (bf16_t)v.x; h[1] = (bf16_t)v.y; h[2] = (bf16_t)v.z; h[3] = (bf16_t)v.w;
  *(bf16x4*)(out + i) = h;
}

// ---------------------------------------------- transpose + cvt: in[K][N] -> out[N][K]
__global__ __launch_bounds__(256) void transpose_cvt_kernel(const float* __restrict__ in,
                                                            bf16_t* __restrict__ out,
                                                            int K, int N) {
  __shared__ float tile[32][33];
  int nb = blockIdx.x * 32, kb = blockIdx.y * 32;
  int tx = threadIdx.x & 31, ty = threadIdx.x >> 5;
#pragma unroll
  for (int r = ty; r < 32; r += 8)
    tile[r][tx] = in[(size_t)(kb + r) * N + nb + tx];
  __syncthreads();
#pragma unroll
  for (int r = ty; r < 32; r += 8)
    out[(size_t)(nb + r) * K + kb + tx] = (bf16_t)tile[tx][r];
}

// ---------------------------------------------------------------- QKV GEMM (m97-style)
__global__ __launch_bounds__(256, 3) void gemm_qkv_kernel(
    const bf16_t* __restrict__ A, const bf16_t* __restrict__ BT,
    const float* __restrict__ bias,
    bf16_t* __restrict__ Qo, bf16_t* __restrict__ Ko, bf16_t* __restrict__ Vo) {
  const int K = 768;
  __shared__ __align__(16) bf16_t As[128 * 32];  // [m][k], unpadded (async staging)
  __shared__ __align__(16) bf16_t Bs[128 * 32];  // [n][k]
  int m0 = blockIdx.x * 128, n0 = blockIdx.y * 128;
  int tid = threadIdx.x;
  int w = tid >> 6, lane = tid & 63, quad = lane >> 4, l16 = lane & 15;
  int wm = (w >> 1) * 64, wn = (w & 1) * 64;
  const bf16_t* gA = A + (size_t)(m0 + w * 32 + (lane >> 2)) * K + (lane & 3) * 8;
  const bf16_t* gB = BT + (size_t)(n0 + w * 32 + (lane >> 2)) * K + (lane & 3) * 8;
  bf16_t* lA = &As[(w * 32) * 32];
  bf16_t* lB = &Bs[(w * 32) * 32];
  floatx4 acc[4][4];
#pragma unroll
  for (int i = 0; i < 4; i++)
#pragma unroll
    for (int j = 0; j < 4; j++) acc[i][j] = (floatx4)(0.f);
  for (int k0 = 0; k0 < K; k0 += 32) {
    __syncthreads();
    async_copy16(gA + k0, lA);
    async_copy16(gA + 16 * K + k0, lA + 16 * 32);
    async_copy16(gB + k0, lB);
    async_copy16(gB + 16 * K + k0, lB + 16 * 32);
    __syncthreads();
    bf16x8 af[4], bfr[4];
#pragma unroll
    for (int i = 0; i < 4; i++)
      af[i] = *(const bf16x8*)&As[(wm + i * 16 + l16) * 32 + quad * 8];
#pragma unroll
    for (int j = 0; j < 4; j++)
      bfr[j] = *(const bf16x8*)&Bs[(wn + j * 16 + l16) * 32 + quad * 8];
#pragma unroll
    for (int i = 0; i < 4; i++)
#pragma unroll
      for (int j = 0; j < 4; j++)
        acc[i][j] = __builtin_amdgcn_mfma_f32_16x16x32_bf16(af[i], bfr[j], acc[i][j], 0, 0, 0);
  }
  int which = n0 / 768;
  bf16_t* dst = which == 0 ? Qo : (which == 1 ? Ko : Vo);
  float qscale = which == 0 ? (0.125f * LOG2E) : 1.0f;
  int rem_base = (n0 % 768) + wn;
#pragma unroll
  for (int j = 0; j < 4; j++) {
    int gc = n0 + wn + j * 16 + l16;
    int rem = rem_base + j * 16 + l16;
    int h = rem >> 6, hd = rem & 63;
    float bv = bias[gc];
#pragma unroll
    for (int i = 0; i < 4; i++)
#pragma unroll
      for (int r = 0; r < 4; r++) {
        int gr = m0 + wm + i * 16 + quad * 4 + r;
        int bb = gr >> 11, s = gr & 2047;
        float val = (acc[i][j][r] + bv) * qscale;
        dst[((size_t)((bb * NH + h) * SEQ + s)) * 64 + hd] = (bf16_t)val;
      }
  }
}

// ---------------------------------------------------------------- V transpose
__global__ __launch_bounds__(256) void vtrans_kernel(const bf16_t* __restrict__ V,
                                                     bf16_t* __restrict__ Vt) {
  __shared__ bf16_t tile[64][66];
  int bh = blockIdx.y, s0 = blockIdx.x * 64;
  int tid = threadIdx.x;
  int r = tid >> 4, c4 = (tid & 15) * 4;
  const bf16_t* src = V + (size_t)bh * SEQ * 64;
#pragma unroll
  for (int rr = r; rr < 64; rr += 16)
    *(bf16x4*)&tile[rr][c4] = *(const bf16x4*)&src[(size_t)(s0 + rr) * 64 + c4];
  __syncthreads();
  bf16_t* dst = Vt + (size_t)bh * 64 * SEQ;
#pragma unroll
  for (int hd = r; hd < 64; hd += 16) {
    bf16x4 o;
    o[0] = tile[c4 + 0][hd]; o[1] = tile[c4 + 1][hd];
    o[2] = tile[c4 + 2][hd]; o[3] = tile[c4 + 3][hd];
    *(bf16x4*)&dst[(size_t)hd * SEQ + s0 + c4] = o;
  }
}

// ---------------------------------------------------------------- flash attention
// 1-wave blocks, grid (64 pairs heavy-first, 48 bh). Each wave owns rows
// [r0, r0+32): two ADJACENT 16-row sets sharing one trip count -> minimal
// iterations. NO occupancy hint: R5's __launch_bounds__(64,4) forced VGPR=64
// -> 286 MB scratch spill. Kernel wants ~120 VGPR (4 waves/SIMD naturally).
__global__ __launch_bounds__(64) void attn_kernel(
    const bf16_t* __restrict__ Q, const bf16_t* __restrict__ Kg,
    const bf16_t* __restrict__ Vt, bf16_t* __restrict__ Out) {
  __shared__ __align__(16) bf16_t Ps[2][16][68];  // per row-set slab
  const int lane = threadIdx.x & 63;
  const int quad = lane >> 4, l16 = lane & 15;
  const int bh = blockIdx.y;
  const int b = bh / NH, h = bh % NH;
  const int r0 = (63 - (int)blockIdx.x) * 32;     // heavy-first
  const bf16_t* Qp = Q + (size_t)bh * SEQ * 64;
  const bf16_t* Kp = Kg + (size_t)bh * SEQ * 64;
  const bf16_t* Vp = Vt + (size_t)bh * 64 * SEQ;

  bf16x8 qf[2][2];
#pragma unroll
  for (int rs = 0; rs < 2; rs++)
#pragma unroll
    for (int hh = 0; hh < 2; hh++)
      qf[rs][hh] = *(const bf16x8*)&Qp[(size_t)(r0 + rs * 16 + l16) * 64 + hh * 32 + quad * 8];

  const int nt = (r0 >> 6) + 1;  // covers keys 0 .. r0+31 (last tile part-masked)

  float m_i[2][4], l_p[2][4];
  floatx4 acc[2][4];
#pragma unroll
  for (int rs = 0; rs < 2; rs++) {
#pragma unroll
    for (int r = 0; r < 4; r++) { m_i[rs][r] = -1e30f; l_p[rs][r] = 0.f; }
#pragma unroll
    for (int ot = 0; ot < 4; ot++) acc[rs][ot] = (floatx4)(0.f);
  }

  for (int kt = 0; kt < nt; kt++) {
    const int kbase = kt * 64;
    // ---- K fragments (direct from global, L2-resident)
    bf16x8 kf[4][2];
#pragma unroll
    for (int ct = 0; ct < 4; ct++)
#pragma unroll
      for (int hh = 0; hh < 2; hh++)
        kf[ct][hh] = *(const bf16x8*)&Kp[(size_t)(kbase + ct * 16 + l16) * 64 + hh * 32 + quad * 8];
    // ---- QK^T: both row-sets, same K fragments
    floatx4 s[2][4];
#pragma unroll
    for (int rs = 0; rs < 2; rs++)
#pragma unroll
      for (int ct = 0; ct < 4; ct++) {
        floatx4 z = (floatx4)(0.f);
        z = __builtin_amdgcn_mfma_f32_16x16x32_bf16(qf[rs][0], kf[ct][0], z, 0, 0, 0);
        z = __builtin_amdgcn_mfma_f32_16x16x32_bf16(qf[rs][1], kf[ct][1], z, 0, 0, 0);
        s[rs][ct] = z;
      }
    // ---- V fragments: issued now, consumed after softmax (fly across VALU)
    bf16x8 vf[4][2];
#pragma unroll
    for (int ot = 0; ot < 4; ot++)
#pragma unroll
      for (int kh = 0; kh < 2; kh++)
        vf[ot][kh] = *(const bf16x8*)&Vp[(size_t)(ot * 16 + l16) * SEQ + kbase + kh * 32 + quad * 8];
    // ---- causal mask (last tile only; both sets)
    if (kt == nt - 1) {
#pragma unroll
      for (int rs = 0; rs < 2; rs++)
#pragma unroll
        for (int ct = 0; ct < 4; ct++) {
          int key = kbase + ct * 16 + l16;
#pragma unroll
          for (int r = 0; r < 4; r++)
            if (key > r0 + rs * 16 + quad * 4 + r) s[rs][ct][r] = -1e30f;
        }
    }
    // ---- online softmax (exp2 domain), both sets; writes to private slabs
    asm volatile("s_waitcnt lgkmcnt(0)" ::: "memory");  // WAR vs prev pf reads
#pragma unroll
    for (int rs = 0; rs < 2; rs++) {
      float alpha_r[4];
#pragma unroll
      for (int r = 0; r < 4; r++) {
        float mt = fmaxf(fmaxf(s[rs][0][r], s[rs][1][r]), fmaxf(s[rs][2][r], s[rs][3][r]));
#pragma unroll
        for (int off = 8; off >= 1; off >>= 1)
          mt = fmaxf(mt, __shfl_xor(mt, off, 16));
        float mnew = fmaxf(m_i[rs][r], mt);
        float al = __builtin_amdgcn_exp2f(m_i[rs][r] - mnew);
        m_i[rs][r] = mnew;
        float p0 = __builtin_amdgcn_exp2f(s[rs][0][r] - mnew);
        float p1 = __builtin_amdgcn_exp2f(s[rs][1][r] - mnew);
        float p2 = __builtin_amdgcn_exp2f(s[rs][2][r] - mnew);
        float p3 = __builtin_amdgcn_exp2f(s[rs][3][r] - mnew);
        Ps[rs][quad * 4 + r][0 * 16 + l16] = (bf16_t)p0;
        Ps[rs][quad * 4 + r][1 * 16 + l16] = (bf16_t)p1;
        Ps[rs][quad * 4 + r][2 * 16 + l16] = (bf16_t)p2;
        Ps[rs][quad * 4 + r][3 * 16 + l16] = (bf16_t)p3;
        l_p[rs][r] = l_p[rs][r] * al + ((p0 + p1) + (p2 + p3));
        alpha_r[r] = al;
      }
#pragma unroll
      for (int ot = 0; ot < 4; ot++)
#pragma unroll
        for (int r = 0; r < 4; r++) acc[rs][ot][r] *= alpha_r[r];
    }
    // ---- P LDS roundtrip -> A-layout, then PV for both sets
    asm volatile("s_waitcnt lgkmcnt(0)" ::: "memory");  // RAW: P writes -> reads
#pragma unroll
    for (int rs = 0; rs < 2; rs++) {
      bf16x8 pf0 = *(const bf16x8*)&Ps[rs][l16][0 * 32 + quad * 8];
      bf16x8 pf1 = *(const bf16x8*)&Ps[rs][l16][1 * 32 + quad * 8];
#pragma unroll
      for (int ot = 0; ot < 4; ot++) {
        acc[rs][ot] = __builtin_amdgcn_mfma_f32_16x16x32_bf16(pf0, vf[ot][0], acc[rs][ot], 0, 0, 0);
        acc[rs][ot] = __builtin_amdgcn_mfma_f32_16x16x32_bf16(pf1, vf[ot][1], acc[rs][ot], 0, 0, 0);
      }
    }
  }
  // ---- epilogue
#pragma unroll
  for (int rs = 0; rs < 2; rs++) {
    float inv_l[4];
#pragma unroll
    for (int r = 0; r < 4; r++) {
      float ls = l_p[rs][r];
#pragma unroll
      for (int off = 8; off >= 1; off >>= 1)
        ls += __shfl_xor(ls, off, 16);
      inv_l[r] = __frcp_rn(ls);
    }
#pragma unroll
    for (int ot = 0; ot < 4; ot++)
#pragma unroll
      for (int r = 0; r < 4; r++) {
        int row = r0 + rs * 16 + quad * 4 + r;
        float o = acc[rs][ot][r] * inv_l[r];
        Out[((size_t)(b * SEQ + row)) * DM + h * 64 + ot * 16 + l16] = (bf16_t)o;
      }
  }
}

// ---------------------------------------------------------------- out-proj GEMM (m97-style)
__global__ __launch_bounds__(256, 3) void gemm_proj_kernel(
    const bf16_t* __restrict__ A, const bf16_t* __restrict__ BT,
    const float* __restrict__ bias, float* __restrict__ out) {
  const int K = 768;
  __shared__ __align__(16) bf16_t As[128 * 32];
  __shared__ __align__(16) bf16_t Bs[128 * 32];
  int m0 = blockIdx.x * 128, n0 = blockIdx.y * 128;
  int tid = threadIdx.x;
  int w = tid >> 6, lane = tid & 63, quad = lane >> 4, l16 = lane & 15;
  int wm = (w >> 1) * 64, wn = (w & 1) * 64;
  const bf16_t* gA = A + (size_t)(m0 + w * 32 + (lane >> 2)) * K + (lane & 3) * 8;
  const bf16_t* gB = BT + (size_t)(n0 + w * 32 + (lane >> 2)) * K + (lane & 3) * 8;
  bf16_t* lA = &As[(w * 32) * 32];
  bf16_t* lB = &Bs[(w * 32) * 32];
  floatx4 acc[4][4];
#pragma unroll
  for (int i = 0; i < 4; i++)
#pragma unroll
    for (int j = 0; j < 4; j++) acc[i][j] = (floatx4)(0.f);
  for (int k0 = 0; k0 < K; k0 += 32) {
    __syncthreads();
    async_copy16(gA + k0, lA);
    async_copy16(gA + 16 * K + k0, lA + 16 * 32);
    async_copy16(gB + k0, lB);
    async_copy16(gB + 16 * K + k0, lB + 16 * 32);
    __syncthreads();
    bf16x8 af[4], bfr[4];
#pragma unroll
    for (int i = 0; i < 4; i++)
      af[i] = *(const bf16x8*)&As[(wm + i * 16 + l16) * 32 + quad * 8];
#pragma unroll
    for (int j = 0; j < 4; j++)
      bfr[j] = *(const bf16x8*)&Bs[(wn + j * 16 + l16) * 32 + quad * 8];
#pragma unroll
    for (int i = 0; i < 4; i++)
#pragma unroll
      for (int j = 0; j < 4; j++)
        acc[i][j] = __builtin_amdgcn_mfma_f32_16x16x32_bf16(af[i], bfr[j], acc[i][j], 0, 0, 0);
  }
#pragma unroll
  for (int j = 0; j < 4; j++) {
    int gc = n0 + wn + j * 16 + l16;
    float bv = bias[gc];
#pragma unroll
    for (int i = 0; i < 4; i++)
#pragma unroll
      for (int r = 0; r < 4; r++) {
        int gr = m0 + wm + i * 16 + quad * 4 + r;
        out[(size_t)gr * 768 + gc] = acc[i][j][r] + bv;
      }
  }
}

// ---------------------------------------------------------------- launch
extern "C" void kernel_launch(void* const* d_in, const int* in_sizes, int n_in,
                              void* d_out, int out_size, void* d_ws, size_t ws_size,
                              hipStream_t stream) {
  const float* x      = (const float*)d_in[0];
  const float* w_qkv  = (const float*)d_in[1];
  const float* b_qkv  = (const float*)d_in[2];
  const float* w_proj = (const float*)d_in[3];
  const float* b_proj = (const float*)d_in[4];
  float* out = (float*)d_out;
  char* ws = (char*)d_ws;

  bf16_t* xb     = (bf16_t*)(ws + 0);         // dead after gemm_qkv; reused as vt
  bf16_t* wqkvT  = (bf16_t*)(ws + 12582912);
  bf16_t* wprojT = (bf16_t*)(ws + 16121856);
  bf16_t* q      = (bf16_t*)(ws + 17301504);
  bf16_t* k      = (bf16_t*)(ws + 29884416);
  bf16_t* v      = (bf16_t*)(ws + 42467328);
  bf16_t* ao     = (bf16_t*)(ws + 55050240);
  bf16_t* vt     = xb;

  cvt_kernel<<<6144, 256, 0, stream>>>(x, xb);
  transpose_cvt_kernel<<<dim3(72, 24), 256, 0, stream>>>(w_qkv, wqkvT, 768, 2304);
  transpose_cvt_kernel<<<dim3(24, 24), 256, 0, stream>>>(w_proj, wprojT, 768, 768);
  gemm_qkv_kernel<<<dim3(64, 18), 256, 0, stream>>>(xb, wqkvT, b_qkv, q, k, v);
  vtrans_kernel<<<dim3(32, 48), 256, 0, stream>>>(v, vt);
  attn_kernel<<<dim3(64, 48), 64, 0, stream>>>(q, k, vt, ao);
  gemm_proj_kernel<<<dim3(64, 6), 256, 0, stream>>>(ao, wprojT, b_proj, out);
}